// Round 1
// baseline (2224.757 us; speedup 1.0000x reference)
//
#include <hip/hip_runtime.h>
#include <hip/hip_bf16.h>
#include <stdint.h>

// ---------------- dropout mask variant ----------------
// 0: partitionable threefry (JAX >= 0.4.36 default): bits = o0 ^ o1, counter = (0, j)
// 1: original split-iota threefry: pair (i, i+2^25), word = j >> 25
// 2: partitionable, word o0      3: partitionable, word o1
#define MASK_VARIANT 0

constexpr int Bn = 16;
constexpr int Nn = 2048;
constexpr int Dn = 768;
constexpr int QT = 32;   // q rows per block
constexpr int KT = 32;   // k cols per tile
constexpr int NTHREADS = 512;  // 8 waves

typedef __attribute__((ext_vector_type(4))) float f32x4;
typedef __attribute__((ext_vector_type(8))) __bf16 bf16x8;

// LDS byte offsets
constexpr int QS_OFF = 0;                        // [32][768] bf16, row-swizzled
constexpr int KS_OFF = QS_OFF + QT * Dn * 2;     // 49152
constexpr int VT_OFF = KS_OFF + KT * Dn * 2;     // 98304: [768][32] bf16, swizzled
constexpr int SP_OFF = VT_OFF + Dn * KT * 2;     // 147456: [2][32][33] f32 partial S
constexpr int P_OFF  = SP_OFF + 2 * QT * 33 * 4; // 155904: [32][32] bf16, swizzled
constexpr int SM_OFF = P_OFF + QT * KT * 2;      // 157952: m,l,rf [32] f32 each
constexpr int SMEM_BYTES = SM_OFF + 3 * QT * 4;  // 158336 (< 163840)

// swizzles: XOR row-dependent bits into byte bits [4:6] -> conflict-free b128 reads
__device__ __forceinline__ int qk_off(int row, int d) {
  return (row * (Dn * 2) + d * 2) ^ ((row & 7) << 4);
}
__device__ __forceinline__ int vt_off(int d, int k) {
  return (d * (KT * 2) + k * 2) ^ ((d & 7) << 4);
}
__device__ __forceinline__ int p_off(int row, int k) {
  return (row * (KT * 2) + k * 2) ^ ((row & 7) << 4);
}

__device__ __forceinline__ uint32_t rotl32(uint32_t x, int r) {
  return (x << r) | (x >> (32 - r));
}

// JAX threefry2x32, key = (0, 42)  (jax.random.key(42) -> [hi=0, lo=42])
__device__ __forceinline__ void threefry2x32(uint32_t x0, uint32_t x1,
                                             uint32_t& o0, uint32_t& o1) {
  const uint32_t ks0 = 0u;
  const uint32_t ks1 = 42u;
  const uint32_t ks2 = 0x1BD11BDAu ^ ks0 ^ ks1;
  x0 += ks0; x1 += ks1;
#define RND(r) { x0 += x1; x1 = rotl32(x1, (r)); x1 ^= x0; }
  RND(13) RND(15) RND(26) RND(6)   x0 += ks1; x1 += ks2 + 1u;
  RND(17) RND(29) RND(16) RND(24)  x0 += ks2; x1 += ks0 + 2u;
  RND(13) RND(15) RND(26) RND(6)   x0 += ks0; x1 += ks1 + 3u;
  RND(17) RND(29) RND(16) RND(24)  x0 += ks1; x1 += ks2 + 4u;
  RND(13) RND(15) RND(26) RND(6)   x0 += ks2; x1 += ks0 + 5u;
#undef RND
  o0 = x0; o1 = x1;
}

__device__ __forceinline__ bool keep_mask(int b, int q, int k) {
  uint32_t j = ((uint32_t)b << 22) | ((uint32_t)q << 11) | (uint32_t)k;
  uint32_t o0, o1;
#if MASK_VARIANT == 0
  threefry2x32(0u, j, o0, o1);
  return ((o0 ^ o1) >> 31) == 0u;   // keep iff uniform < 0.5 iff MSB == 0
#elif MASK_VARIANT == 1
  uint32_t i = j & 0x01FFFFFFu;
  threefry2x32(i, i + 0x02000000u, o0, o1);
  uint32_t bits = (j >> 25) ? o1 : o0;
  return (bits >> 31) == 0u;
#elif MASK_VARIANT == 2
  threefry2x32(0u, j, o0, o1);
  return (o0 >> 31) == 0u;
#else
  threefry2x32(0u, j, o0, o1);
  return (o1 >> 31) == 0u;
#endif
}

__global__ __launch_bounds__(NTHREADS, 2)
void attn_kernel(const float* __restrict__ in, float* __restrict__ out) {
  __shared__ __align__(16) unsigned char smem[SMEM_BYTES];
  unsigned char* Qs = smem + QS_OFF;
  unsigned char* Ks = smem + KS_OFF;
  unsigned char* VT = smem + VT_OFF;
  float* Sp = (float*)(smem + SP_OFF);     // [2][32][33]
  unsigned char* Pm = smem + P_OFF;
  float* sm_m  = (float*)(smem + SM_OFF);
  float* sm_l  = sm_m + QT;
  float* sm_rf = sm_m + 2 * QT;

  const int t = threadIdx.x;
  // XCD-aware remap: linear block L -> xcd = L&7 owns batches {2*(L&7), 2*(L&7)+1}
  const int L = blockIdx.x;
  const int b  = ((L & 7) << 1) | ((L >> 3) & 1);
  const int q0 = (L >> 4) * QT;

  const int w   = t >> 6;   // wave 0..7
  const int l   = t & 63;
  const int l15 = l & 15;
  const int g   = l >> 4;   // 0..3

  const float scale = 0.03608439182435161f; // 1/sqrt(768)

  const float* Qg = in + ((size_t)b * Nn + q0) * Dn;
  const float* Kg = in + (size_t)b * Nn * Dn;

  // ---- stage Q once (scaled, bf16, swizzled) ----
  {
    int row = t >> 4;
    int cbase = (t & 15) * 8;
    const float* src = Qg + (size_t)row * Dn;
#pragma unroll
    for (int i = 0; i < 6; ++i) {
      int d0 = cbase + 128 * i;
      f32x4 a = *reinterpret_cast<const f32x4*>(src + d0);
      f32x4 c = *reinterpret_cast<const f32x4*>(src + d0 + 4);
      bf16x8 h;
      h[0] = (__bf16)(a[0] * scale); h[1] = (__bf16)(a[1] * scale);
      h[2] = (__bf16)(a[2] * scale); h[3] = (__bf16)(a[3] * scale);
      h[4] = (__bf16)(c[0] * scale); h[5] = (__bf16)(c[1] * scale);
      h[6] = (__bf16)(c[2] * scale); h[7] = (__bf16)(c[3] * scale);
      *reinterpret_cast<bf16x8*>(Qs + qk_off(row, d0)) = h;
    }
  }
  if (t < QT) { sm_m[t] = -1e30f; sm_l[t] = 0.0f; }

  f32x4 acc[12];
#pragma unroll
  for (int i = 0; i < 12; ++i) acc[i] = (f32x4){0.f, 0.f, 0.f, 0.f};

  // wave roles
  const int qk_pair = w >> 1;            // 0..3 -> (m,n) subtile of S
  const int qk_m = qk_pair >> 1, qk_n = qk_pair & 1, qk_h = w & 1; // h: d-half
  const int pv_m = w >> 2;               // 0..1
  const int pv_dblk = (w & 3) * 192;     // d-range base for PV/out

#pragma unroll 1
  for (int kt = 0; kt < Nn / KT; ++kt) {
    __syncthreads();  // prev PV done reading Ks/VT
    // ---- stage K tile (bf16 swizzled) + V^T copy ----
    {
      int row = t >> 4;
      int cbase = (t & 15) * 8;
      const float* src = Kg + ((size_t)(kt * KT + row)) * Dn;
#pragma unroll
      for (int i = 0; i < 6; ++i) {
        int d0 = cbase + 128 * i;
        f32x4 a = *reinterpret_cast<const f32x4*>(src + d0);
        f32x4 c = *reinterpret_cast<const f32x4*>(src + d0 + 4);
        bf16x8 h;
        h[0] = (__bf16)a[0]; h[1] = (__bf16)a[1];
        h[2] = (__bf16)a[2]; h[3] = (__bf16)a[3];
        h[4] = (__bf16)c[0]; h[5] = (__bf16)c[1];
        h[6] = (__bf16)c[2]; h[7] = (__bf16)c[3];
        *reinterpret_cast<bf16x8*>(Ks + qk_off(row, d0)) = h;
#pragma unroll
        for (int jj = 0; jj < 8; ++jj) {
          *reinterpret_cast<__bf16*>(VT + vt_off(d0 + jj, row)) = h[jj];
        }
      }
    }
    __syncthreads();
    // ---- QK^T: partial over this wave's d-half ----
    {
      f32x4 s = (f32x4){0.f, 0.f, 0.f, 0.f};
#pragma unroll
      for (int dk = 0; dk < 12; ++dk) {
        int d = qk_h * 384 + dk * 32 + g * 8;
        bf16x8 aq = *reinterpret_cast<const bf16x8*>(Qs + qk_off(qk_m * 16 + l15, d));
        bf16x8 bk = *reinterpret_cast<const bf16x8*>(Ks + qk_off(qk_n * 16 + l15, d));
        s = __builtin_amdgcn_mfma_f32_16x16x32_bf16(aq, bk, s, 0, 0, 0);
      }
      float* dst = Sp + qk_h * (QT * 33) + (qk_m * 16 + g * 4) * 33 + qk_n * 16 + l15;
      dst[0] = s[0]; dst[33] = s[1]; dst[66] = s[2]; dst[99] = s[3];
    }
    __syncthreads();
    // ---- softmax (online) + dropout -> P ----
    {
      int row = t >> 4;
      int c = t & 15;
      float s0 = Sp[row * 33 + c]      + Sp[QT * 33 + row * 33 + c];
      float s1 = Sp[row * 33 + c + 16] + Sp[QT * 33 + row * 33 + c + 16];
      float tmax = fmaxf(s0, s1);
#pragma unroll
      for (int mm = 1; mm <= 8; mm <<= 1) tmax = fmaxf(tmax, __shfl_xor(tmax, mm));
      float m_old = sm_m[row];
      float m_new = fmaxf(m_old, tmax);
      float p0 = __expf(s0 - m_new);
      float p1 = __expf(s1 - m_new);
      float tsum = p0 + p1;
#pragma unroll
      for (int mm = 1; mm <= 8; mm <<= 1) tsum += __shfl_xor(tsum, mm);
      float rf = __expf(m_old - m_new);
      if (c == 0) {
        sm_m[row] = m_new;
        sm_l[row] = sm_l[row] * rf + tsum;
        sm_rf[row] = rf;
      }
      int qg = q0 + row;
      int kg0 = kt * KT + c;
      float pd0 = keep_mask(b, qg, kg0)      ? 2.0f * p0 : 0.0f;
      float pd1 = keep_mask(b, qg, kg0 + 16) ? 2.0f * p1 : 0.0f;
      *reinterpret_cast<__bf16*>(Pm + p_off(row, c))      = (__bf16)pd0;
      *reinterpret_cast<__bf16*>(Pm + p_off(row, c + 16)) = (__bf16)pd1;
    }
    __syncthreads();
    // ---- PV: rescale acc, accumulate P(16x32) * V(32x192-slice) ----
    {
      float rfv[4];
#pragma unroll
      for (int r = 0; r < 4; ++r) rfv[r] = sm_rf[pv_m * 16 + g * 4 + r];
      bf16x8 pa = *reinterpret_cast<const bf16x8*>(Pm + p_off(pv_m * 16 + l15, g * 8));
#pragma unroll
      for (int nn = 0; nn < 12; ++nn) {
        int d0 = pv_dblk + nn * 16;
        acc[nn][0] *= rfv[0]; acc[nn][1] *= rfv[1];
        acc[nn][2] *= rfv[2]; acc[nn][3] *= rfv[3];
        bf16x8 vb = *reinterpret_cast<const bf16x8*>(VT + vt_off(d0 + l15, g * 8));
        acc[nn] = __builtin_amdgcn_mfma_f32_16x16x32_bf16(pa, vb, acc[nn], 0, 0, 0);
      }
    }
  }
  __syncthreads();
  // ---- epilogue: divide by softmax denom, store f32 ----
  {
    float linv[4];
#pragma unroll
    for (int r = 0; r < 4; ++r) linv[r] = 1.0f / sm_l[pv_m * 16 + g * 4 + r];
#pragma unroll
    for (int nn = 0; nn < 12; ++nn) {
      int d = pv_dblk + nn * 16 + l15;
#pragma unroll
      for (int r = 0; r < 4; ++r) {
        int qg = q0 + pv_m * 16 + g * 4 + r;
        out[((size_t)b * Nn + qg) * Dn + d] = acc[nn][r] * linv[r];
      }
    }
  }
}

extern "C" void kernel_launch(void* const* d_in, const int* in_sizes, int n_in,
                              void* d_out, int out_size, void* d_ws, size_t ws_size,
                              hipStream_t stream) {
  (void)in_sizes; (void)n_in; (void)d_ws; (void)ws_size; (void)out_size;
  const float* in = (const float*)d_in[0];
  float* out = (float*)d_out;
  dim3 grid(Bn * (Nn / QT), 1, 1);  // 1024 blocks, XCD-swizzled inside
  attn_kernel<<<grid, NTHREADS, 0, stream>>>(in, out);
}

// Round 2
// 1238.953 us; speedup vs baseline: 1.7957x; 1.7957x over previous
//
#include <hip/hip_runtime.h>
#include <hip/hip_bf16.h>
#include <stdint.h>

// ---------------- dropout mask variant ----------------
// 0: partitionable threefry (JAX >= 0.4.36 default) -- VERIFIED correct (round 1)
#define MASK_VARIANT 0

constexpr int Bn = 16;
constexpr int Nn = 2048;
constexpr int Dn = 768;
constexpr int QT = 32;   // q rows per block
constexpr int KT = 32;   // k cols per tile
constexpr int NTHREADS = 512;  // 8 waves

typedef __attribute__((ext_vector_type(4))) float f32x4;
typedef __attribute__((ext_vector_type(8))) __bf16 bf16x8;
typedef __attribute__((ext_vector_type(4))) __bf16 bf16x4;

// LDS byte offsets
constexpr int QS_OFF = 0;                        // [32][768] bf16, row-swizzled
constexpr int KS_OFF = QS_OFF + QT * Dn * 2;     // 49152
constexpr int VT_OFF = KS_OFF + KT * Dn * 2;     // 98304: [768][32] bf16, swizzled
constexpr int SP_OFF = VT_OFF + Dn * KT * 2;     // 147456: [2][32][33] f32 partial S
constexpr int P_OFF  = SP_OFF + 2 * QT * 33 * 4; // 155904: [32][32] bf16, swizzled
constexpr int SM_OFF = P_OFF + QT * KT * 2;      // 157952: m,l,rf [32] f32 each
constexpr int SMEM_BYTES = SM_OFF + 3 * QT * 4;  // 158336 (< 163840)

// swizzles: XOR row-dependent bits into byte bits [4:6] -> conflict-free b128 reads
__device__ __forceinline__ int qk_off(int row, int d) {
  return (row * (Dn * 2) + d * 2) ^ ((row & 7) << 4);
}
__device__ __forceinline__ int vt_off(int d, int k) {
  return (d * (KT * 2) + k * 2) ^ ((d & 7) << 4);
}
__device__ __forceinline__ int p_off(int row, int k) {
  return (row * (KT * 2) + k * 2) ^ ((row & 7) << 4);
}

__device__ __forceinline__ uint32_t rotl32(uint32_t x, int r) {
  return (x << r) | (x >> (32 - r));
}

// JAX threefry2x32, key = (0, 42)
__device__ __forceinline__ void threefry2x32(uint32_t x0, uint32_t x1,
                                             uint32_t& o0, uint32_t& o1) {
  const uint32_t ks0 = 0u;
  const uint32_t ks1 = 42u;
  const uint32_t ks2 = 0x1BD11BDAu ^ ks0 ^ ks1;
  x0 += ks0; x1 += ks1;
#define RND(r) { x0 += x1; x1 = rotl32(x1, (r)); x1 ^= x0; }
  RND(13) RND(15) RND(26) RND(6)   x0 += ks1; x1 += ks2 + 1u;
  RND(17) RND(29) RND(16) RND(24)  x0 += ks2; x1 += ks0 + 2u;
  RND(13) RND(15) RND(26) RND(6)   x0 += ks0; x1 += ks1 + 3u;
  RND(17) RND(29) RND(16) RND(24)  x0 += ks1; x1 += ks2 + 4u;
  RND(13) RND(15) RND(26) RND(6)   x0 += ks2; x1 += ks0 + 5u;
#undef RND
  o0 = x0; o1 = x1;
}

__device__ __forceinline__ bool keep_mask(int b, int q, int k) {
  uint32_t j = ((uint32_t)b << 22) | ((uint32_t)q << 11) | (uint32_t)k;
  uint32_t o0, o1;
  threefry2x32(0u, j, o0, o1);
  return ((o0 ^ o1) >> 31) == 0u;   // keep iff uniform < 0.5 iff MSB == 0
}

__global__ __launch_bounds__(NTHREADS, 2)
void attn_kernel(const float* __restrict__ in, float* __restrict__ out) {
  __shared__ __align__(16) unsigned char smem[SMEM_BYTES];
  unsigned char* Qs = smem + QS_OFF;
  unsigned char* Ks = smem + KS_OFF;
  unsigned char* VT = smem + VT_OFF;
  float* Sp = (float*)(smem + SP_OFF);     // [2][32][33]
  unsigned char* Pm = smem + P_OFF;
  float* sm_m  = (float*)(smem + SM_OFF);
  float* sm_l  = sm_m + QT;
  float* sm_rf = sm_m + 2 * QT;

  const int t = threadIdx.x;
  const int L = blockIdx.x;
  const int b  = ((L & 7) << 1) | ((L >> 3) & 1);
  const int q0 = (L >> 4) * QT;

  const int w   = t >> 6;   // wave 0..7
  const int l   = t & 63;
  const int l15 = l & 15;
  const int g   = l >> 4;   // 0..3

  const float scale = 0.03608439182435161f; // 1/sqrt(768)

  const float* Qg = in + ((size_t)b * Nn + q0) * Dn;
  const float* Kg = in + (size_t)b * Nn * Dn;

  // ---- stage Q once (scaled, bf16, swizzled) ----
  {
    int row = t >> 4;
    int cbase = (t & 15) * 8;
    const float* src = Qg + (size_t)row * Dn;
#pragma unroll
    for (int i = 0; i < 6; ++i) {
      int d0 = cbase + 128 * i;
      f32x4 a = *reinterpret_cast<const f32x4*>(src + d0);
      f32x4 c = *reinterpret_cast<const f32x4*>(src + d0 + 4);
      bf16x8 h;
      h[0] = (__bf16)(a[0] * scale); h[1] = (__bf16)(a[1] * scale);
      h[2] = (__bf16)(a[2] * scale); h[3] = (__bf16)(a[3] * scale);
      h[4] = (__bf16)(c[0] * scale); h[5] = (__bf16)(c[1] * scale);
      h[6] = (__bf16)(c[2] * scale); h[7] = (__bf16)(c[3] * scale);
      *reinterpret_cast<bf16x8*>(Qs + qk_off(row, d0)) = h;
    }
  }
  if (t < QT) { sm_m[t] = -1e30f; sm_l[t] = 0.0f; }

  f32x4 acc[12];
#pragma unroll
  for (int i = 0; i < 12; ++i) acc[i] = (f32x4){0.f, 0.f, 0.f, 0.f};

  // wave roles
  const int qk_pair = w >> 1;            // 0..3 -> (m,n) subtile of S
  const int qk_m = qk_pair >> 1, qk_n = qk_pair & 1, qk_h = w & 1; // h: d-half
  const int pv_m = w >> 2;               // 0..1
  const int pv_dblk = (w & 3) * 192;     // d-range base for PV/out

#pragma unroll 1
  for (int kt = 0; kt < Nn / KT; ++kt) {
    __syncthreads();  // prev PV done reading Ks/VT
    // ---- stage K tile (bf16 swizzled), row-major copy ----
    {
      int row = t >> 4;
      int cbase = (t & 15) * 8;
      const float* src = Kg + ((size_t)(kt * KT + row)) * Dn;
#pragma unroll
      for (int i = 0; i < 6; ++i) {
        int d0 = cbase + 128 * i;
        f32x4 a = *reinterpret_cast<const f32x4*>(src + d0);
        f32x4 c = *reinterpret_cast<const f32x4*>(src + d0 + 4);
        bf16x8 h;
        h[0] = (__bf16)a[0]; h[1] = (__bf16)a[1];
        h[2] = (__bf16)a[2]; h[3] = (__bf16)a[3];
        h[4] = (__bf16)c[0]; h[5] = (__bf16)c[1];
        h[6] = (__bf16)c[2]; h[7] = (__bf16)c[3];
        *reinterpret_cast<bf16x8*>(Ks + qk_off(row, d0)) = h;
      }
    }
    // ---- stage V^T via transposed-mapping global re-read ----
    // wave w owns k rows 4w..4w+3; lane l owns d-column it*64+l.
    // Global loads: 64 consecutive dwords/wave-instr (coalesced, L1/L2-hot).
    // LDS writes: b64, d&7 = l&7 varies per lane -> ~conflict-free.
    {
      const float* vsrc = Kg + ((size_t)(kt * KT + 4 * w)) * Dn;
#pragma unroll
      for (int it = 0; it < 12; ++it) {
        int d = it * 64 + l;
        float v0 = vsrc[d];
        float v1 = vsrc[Dn + d];
        float v2 = vsrc[2 * Dn + d];
        float v3 = vsrc[3 * Dn + d];
        bf16x4 hv;
        hv[0] = (__bf16)v0; hv[1] = (__bf16)v1;
        hv[2] = (__bf16)v2; hv[3] = (__bf16)v3;
        *reinterpret_cast<bf16x4*>(VT + vt_off(d, 4 * w)) = hv;
      }
    }
    __syncthreads();
    // ---- QK^T: partial over this wave's d-half ----
    {
      f32x4 s = (f32x4){0.f, 0.f, 0.f, 0.f};
#pragma unroll
      for (int dk = 0; dk < 12; ++dk) {
        int d = qk_h * 384 + dk * 32 + g * 8;
        bf16x8 aq = *reinterpret_cast<const bf16x8*>(Qs + qk_off(qk_m * 16 + l15, d));
        bf16x8 bk = *reinterpret_cast<const bf16x8*>(Ks + qk_off(qk_n * 16 + l15, d));
        s = __builtin_amdgcn_mfma_f32_16x16x32_bf16(aq, bk, s, 0, 0, 0);
      }
      float* dst = Sp + qk_h * (QT * 33) + (qk_m * 16 + g * 4) * 33 + qk_n * 16 + l15;
      dst[0] = s[0]; dst[33] = s[1]; dst[66] = s[2]; dst[99] = s[3];
    }
    __syncthreads();
    // ---- softmax (online) + dropout -> P ----
    {
      int row = t >> 4;
      int c = t & 15;
      float s0 = Sp[row * 33 + c]      + Sp[QT * 33 + row * 33 + c];
      float s1 = Sp[row * 33 + c + 16] + Sp[QT * 33 + row * 33 + c + 16];
      float tmax = fmaxf(s0, s1);
#pragma unroll
      for (int mm = 1; mm <= 8; mm <<= 1) tmax = fmaxf(tmax, __shfl_xor(tmax, mm));
      float m_old = sm_m[row];
      float m_new = fmaxf(m_old, tmax);
      float p0 = __expf(s0 - m_new);
      float p1 = __expf(s1 - m_new);
      float tsum = p0 + p1;
#pragma unroll
      for (int mm = 1; mm <= 8; mm <<= 1) tsum += __shfl_xor(tsum, mm);
      float rf = __expf(m_old - m_new);
      if (c == 0) {
        sm_m[row] = m_new;
        sm_l[row] = sm_l[row] * rf + tsum;
        sm_rf[row] = rf;
      }
      int qg = q0 + row;
      int kg0 = kt * KT + c;
      float pd0 = keep_mask(b, qg, kg0)      ? 2.0f * p0 : 0.0f;
      float pd1 = keep_mask(b, qg, kg0 + 16) ? 2.0f * p1 : 0.0f;
      *reinterpret_cast<__bf16*>(Pm + p_off(row, c))      = (__bf16)pd0;
      *reinterpret_cast<__bf16*>(Pm + p_off(row, c + 16)) = (__bf16)pd1;
    }
    __syncthreads();
    // ---- PV: rescale acc, accumulate P(16x32) * V(32x192-slice) ----
    {
      float rfv[4];
#pragma unroll
      for (int r = 0; r < 4; ++r) rfv[r] = sm_rf[pv_m * 16 + g * 4 + r];
      bf16x8 pa = *reinterpret_cast<const bf16x8*>(Pm + p_off(pv_m * 16 + l15, g * 8));
#pragma unroll
      for (int nn = 0; nn < 12; ++nn) {
        int d0 = pv_dblk + nn * 16;
        acc[nn][0] *= rfv[0]; acc[nn][1] *= rfv[1];
        acc[nn][2] *= rfv[2]; acc[nn][3] *= rfv[3];
        bf16x8 vb = *reinterpret_cast<const bf16x8*>(VT + vt_off(d0 + l15, g * 8));
        acc[nn] = __builtin_amdgcn_mfma_f32_16x16x32_bf16(pa, vb, acc[nn], 0, 0, 0);
      }
    }
  }
  __syncthreads();
  // ---- epilogue: divide by softmax denom, store f32 ----
  {
    float linv[4];
#pragma unroll
    for (int r = 0; r < 4; ++r) linv[r] = 1.0f / sm_l[pv_m * 16 + g * 4 + r];
#pragma unroll
    for (int nn = 0; nn < 12; ++nn) {
      int d = pv_dblk + nn * 16 + l15;
#pragma unroll
      for (int r = 0; r < 4; ++r) {
        int qg = q0 + pv_m * 16 + g * 4 + r;
        out[((size_t)b * Nn + qg) * Dn + d] = acc[nn][r] * linv[r];
      }
    }
  }
}

extern "C" void kernel_launch(void* const* d_in, const int* in_sizes, int n_in,
                              void* d_out, int out_size, void* d_ws, size_t ws_size,
                              hipStream_t stream) {
  (void)in_sizes; (void)n_in; (void)d_ws; (void)ws_size; (void)out_size;
  const float* in = (const float*)d_in[0];
  float* out = (float*)d_out;
  dim3 grid(Bn * (Nn / QT), 1, 1);  // 1024 blocks, XCD-swizzled inside
  attn_kernel<<<grid, NTHREADS, 0, stream>>>(in, out);
}

// Round 3
// 989.289 us; speedup vs baseline: 2.2488x; 1.2524x over previous
//
#include <hip/hip_runtime.h>
#include <hip/hip_bf16.h>
#include <stdint.h>

constexpr int Bn = 16;
constexpr int Nn = 2048;
constexpr int Dn = 768;
constexpr int NT = 64;          // k-tiles of 32
constexpr int TILEB = 32 * 768 * 2;  // 49152 bytes per tile image

typedef __attribute__((ext_vector_type(4))) float f32x4;
typedef __attribute__((ext_vector_type(8))) __bf16 bf16x8;

// ---- swizzled tile-image offsets (shared by pre-pass writer and hot reader) ----
__device__ __forceinline__ int qk_off(int row, int d) {   // [32][768] bf16
  return (row * (Dn * 2) + d * 2) ^ ((row & 7) << 4);
}
__device__ __forceinline__ int vt_off(int d, int k) {     // [768][32] bf16
  return (d * 64 + k * 2) ^ ((d & 7) << 4);
}
__device__ __forceinline__ int p_off(int row, int k) {    // [64][32] bf16
  return (row * 64 + k * 2) ^ ((row & 7) << 4);
}

__device__ __forceinline__ uint32_t rotl32(uint32_t x, int r) {
  return (x << r) | (x >> (32 - r));
}
// JAX threefry2x32, key (0,42) -- verified round 1
__device__ __forceinline__ void threefry2x32(uint32_t x0, uint32_t x1,
                                             uint32_t& o0, uint32_t& o1) {
  const uint32_t ks0 = 0u, ks1 = 42u;
  const uint32_t ks2 = 0x1BD11BDAu ^ ks0 ^ ks1;
  x0 += ks0; x1 += ks1;
#define RND(r) { x0 += x1; x1 = rotl32(x1, (r)); x1 ^= x0; }
  RND(13) RND(15) RND(26) RND(6)   x0 += ks1; x1 += ks2 + 1u;
  RND(17) RND(29) RND(16) RND(24)  x0 += ks2; x1 += ks0 + 2u;
  RND(13) RND(15) RND(26) RND(6)   x0 += ks0; x1 += ks1 + 3u;
  RND(17) RND(29) RND(16) RND(24)  x0 += ks1; x1 += ks2 + 4u;
  RND(13) RND(15) RND(26) RND(6)   x0 += ks2; x1 += ks0 + 5u;
#undef RND
  o0 = x0; o1 = x1;
}

__device__ __forceinline__ void gload_lds16(const void* g, void* l) {
  __builtin_amdgcn_global_load_lds(
      (const __attribute__((address_space(1))) void*)g,
      (__attribute__((address_space(3))) void*)l, 16, 0, 0);
}

// =================== pre-pass 1: f32 -> bf16 swizzled tile images ===================
__global__ __launch_bounds__(256)
void prepass_cvt(const float* __restrict__ in, uint8_t* __restrict__ Kc,
                 uint8_t* __restrict__ Vc) {
  const int t = threadIdx.x;
  const size_t tile = blockIdx.x;            // = b*64 + ti
  const float* src = in + tile * (size_t)(32 * Dn);
  uint8_t* Kt = Kc + tile * (size_t)TILEB;
  uint8_t* Vt = Vc + tile * (size_t)TILEB;
  // K path: row-major copy
  {
    int row = t >> 3, c0 = (t & 7) * 8;
    const float* rs = src + (size_t)row * Dn;
#pragma unroll
    for (int i = 0; i < 12; ++i) {
      int d = c0 + i * 64;
      f32x4 a = *reinterpret_cast<const f32x4*>(rs + d);
      f32x4 b4 = *reinterpret_cast<const f32x4*>(rs + d + 4);
      bf16x8 h;
      h[0] = (__bf16)a[0]; h[1] = (__bf16)a[1]; h[2] = (__bf16)a[2]; h[3] = (__bf16)a[3];
      h[4] = (__bf16)b4[0]; h[5] = (__bf16)b4[1]; h[6] = (__bf16)b4[2]; h[7] = (__bf16)b4[3];
      *reinterpret_cast<bf16x8*>(Kt + qk_off(row, d)) = h;
    }
  }
  // V^T path: column gather (coalesced across threads: consecutive t -> consecutive d)
#pragma unroll
  for (int s = 0; s < 3; ++s) {
    int d = t + 256 * s;
#pragma unroll
    for (int u = 0; u < 4; ++u) {
      bf16x8 h;
#pragma unroll
      for (int k2 = 0; k2 < 8; ++k2)
        h[k2] = (__bf16)src[(size_t)(u * 8 + k2) * Dn + d];
      *reinterpret_cast<bf16x8*>(Vt + vt_off(d, u * 8)) = h;
    }
  }
}

// =================== pre-pass 2: bit-packed dropout mask ===================
__global__ __launch_bounds__(256)
void prepass_mask(uint32_t* __restrict__ MaskW) {
  unsigned j = blockIdx.x * 256u + threadIdx.x;   // flat element index, < 2^26
  uint32_t o0, o1;
  threefry2x32(0u, j, o0, o1);
  unsigned long long bal = __ballot(((o0 ^ o1) >> 31) == 0u);
  if ((threadIdx.x & 63) == 0)
    reinterpret_cast<unsigned long long*>(MaskW)[j >> 6] = bal;
}

// =================== main flash-attention kernel ===================
// LDS layout
constexpr int KS_OFF = 0;                 // 49152
constexpr int VT_OFF = 49152;             // 49152
constexpr int SP_OFF = 98304;             // f32 [4][64][34] = 34816
constexpr int P_OFF  = 133120;            // [64][32] bf16 swz = 4096
constexpr int SM_OFF = 137216;            // m[64], l[64], rf[64] f32
constexpr int LDS_TOTAL = 137984;
constexpr int SPQ = 64 * 34;              // f32 stride per q-quarter

__global__ __launch_bounds__(1024, 4)
void attn_main(const uint8_t* __restrict__ Kc, const uint8_t* __restrict__ Vc,
               const uint32_t* __restrict__ Mask, float* __restrict__ out) {
  __shared__ __align__(16) uint8_t lds[LDS_TOTAL];
  uint8_t* Ks = lds + KS_OFF;
  uint8_t* VT = lds + VT_OFF;
  float* Sp = (float*)(lds + SP_OFF);
  uint8_t* Pm = lds + P_OFF;
  float* sm_m = (float*)(lds + SM_OFF);
  float* sm_l = sm_m + 64;
  float* sm_rf = sm_m + 128;

  const int t = threadIdx.x;
  const int w = t >> 6, l = t & 63, l15 = l & 15, g = l >> 4;
  // block map: 512 blocks; xcd = L&7 owns batches {2x,2x+1}
  const int L = blockIdx.x;
  const int b = ((L & 7) << 1) | (L >> 8);
  const int qhat = (L >> 3) & 31;
  const int q0 = qhat << 6;

  // QK^T roles: m2 x n2 x q4 ; PV roles: m2 x dg8
  const int qm = w >> 3, qn = (w >> 2) & 1, qq = w & 3;
  const int pm = w >> 3, dblk = (w & 7) * 96;

  const float scale = 0.03608439182435161f;  // 1/sqrt(768)
  const size_t bt = (size_t)b * NT;

  // ---- prologue: Q fragments to registers; issue Ks[0]; init sm ----
  bf16x8 Qf0[6], Qf1[6];
  {
    const uint8_t* qtile = Kc + (bt + qhat * 2 + qm) * (size_t)TILEB;
#pragma unroll
    for (int dk = 0; dk < 6; ++dk) {
      int d = qq * 192 + dk * 32 + g * 8;
      Qf0[dk] = *reinterpret_cast<const bf16x8*>(qtile + qk_off(l15, d));
      Qf1[dk] = *reinterpret_cast<const bf16x8*>(qtile + qk_off(16 + l15, d));
    }
  }
  {
    const uint8_t* kg = Kc + bt * (size_t)TILEB;
#pragma unroll
    for (int i = 0; i < 3; ++i) {
      int off = (w * 3 + i) * 1024 + l * 16;
      gload_lds16(kg + off, Ks + off);
    }
  }
  if (t < 64) { sm_m[t] = -1e30f; sm_l[t] = 0.0f; }

  f32x4 acc0[6], acc1[6];
#pragma unroll
  for (int i = 0; i < 6; ++i) { acc0[i] = (f32x4){0,0,0,0}; acc1[i] = (f32x4){0,0,0,0}; }

  asm volatile("s_waitcnt vmcnt(0) lgkmcnt(0)" ::: "memory");
  __builtin_amdgcn_s_barrier();               // (a) entering iter 0

#pragma unroll 1
  for (int kt = 0; kt < NT; ++kt) {
    // ---- segment A: issue VT[kt] stage; QK^T from Ks ----
    {
      const uint8_t* vg = Vc + (bt + kt) * (size_t)TILEB;
#pragma unroll
      for (int i = 0; i < 3; ++i) {
        int off = (w * 3 + i) * 1024 + l * 16;
        gload_lds16(vg + off, VT + off);
      }
    }
    f32x4 s0 = (f32x4){0,0,0,0}, s1 = (f32x4){0,0,0,0};
    __builtin_amdgcn_s_setprio(1);
#pragma unroll
    for (int dk = 0; dk < 6; ++dk) {
      int d = qq * 192 + dk * 32 + g * 8;
      bf16x8 bk = *reinterpret_cast<const bf16x8*>(Ks + qk_off(qn * 16 + l15, d));
      s0 = __builtin_amdgcn_mfma_f32_16x16x32_bf16(Qf0[dk], bk, s0, 0, 0, 0);
      s1 = __builtin_amdgcn_mfma_f32_16x16x32_bf16(Qf1[dk], bk, s1, 0, 0, 0);
    }
    __builtin_amdgcn_s_setprio(0);
    {
      float* dp = Sp + qq * SPQ + (qm * 32 + g * 4) * 34 + qn * 16 + l15;
      dp[0] = s0[0]; dp[34] = s0[1]; dp[68] = s0[2]; dp[102] = s0[3];
      float* dp1 = dp + 16 * 34;
      dp1[0] = s1[0]; dp1[34] = s1[1]; dp1[68] = s1[2]; dp1[102] = s1[3];
    }
    asm volatile("s_waitcnt lgkmcnt(0)" ::: "memory");
    __builtin_amdgcn_s_barrier();             // (b)
    // ---- segment B: issue Ks[kt+1] (wrapped on last iter); softmax ----
    {
      const uint8_t* kg = Kc + (bt + ((kt + 1) & (NT - 1))) * (size_t)TILEB;
#pragma unroll
      for (int i = 0; i < 3; ++i) {
        int off = (w * 3 + i) * 1024 + l * 16;
        gload_lds16(kg + off, Ks + off);
      }
    }
    {
      int row = t >> 4, c = t & 15;
      uint32_t mw = Mask[(((uint32_t)b << 11) + (uint32_t)(q0 + row)) * 64u + (uint32_t)kt];
      int sb = row * 34 + c;
      float s0v = Sp[sb] + Sp[sb + SPQ] + Sp[sb + 2 * SPQ] + Sp[sb + 3 * SPQ];
      float s1v = Sp[sb + 16] + Sp[sb + 16 + SPQ] + Sp[sb + 16 + 2 * SPQ] + Sp[sb + 16 + 3 * SPQ];
      s0v *= scale; s1v *= scale;
      float tmax = fmaxf(s0v, s1v);
#pragma unroll
      for (int mm = 1; mm <= 8; mm <<= 1) tmax = fmaxf(tmax, __shfl_xor(tmax, mm));
      float m_old = sm_m[row];
      float m_new = fmaxf(m_old, tmax);
      float p0 = __expf(s0v - m_new), p1 = __expf(s1v - m_new);
      float ts = p0 + p1;
#pragma unroll
      for (int mm = 1; mm <= 8; mm <<= 1) ts += __shfl_xor(ts, mm);
      float rf = __expf(m_old - m_new);
      if (c == 0) {
        sm_m[row] = m_new;
        sm_l[row] = sm_l[row] * rf + ts;
        sm_rf[row] = rf;
      }
      float pd0 = ((mw >> c) & 1u) ? p0 + p0 : 0.0f;
      float pd1 = ((mw >> (c + 16)) & 1u) ? p1 + p1 : 0.0f;
      *reinterpret_cast<__bf16*>(Pm + p_off(row, c)) = (__bf16)pd0;
      *reinterpret_cast<__bf16*>(Pm + p_off(row, c + 16)) = (__bf16)pd1;
    }
    asm volatile("s_waitcnt vmcnt(4) lgkmcnt(0)" ::: "memory");  // VT[kt] resident
    __builtin_amdgcn_s_barrier();             // (c)
    // ---- segment C: PV ----
    {
      float rf0[4], rf1[4];
#pragma unroll
      for (int r = 0; r < 4; ++r) {
        rf0[r] = sm_rf[pm * 32 + g * 4 + r];
        rf1[r] = sm_rf[pm * 32 + 16 + g * 4 + r];
      }
      bf16x8 pa0 = *reinterpret_cast<const bf16x8*>(Pm + p_off(pm * 32 + l15, g * 8));
      bf16x8 pa1 = *reinterpret_cast<const bf16x8*>(Pm + p_off(pm * 32 + 16 + l15, g * 8));
      __builtin_amdgcn_s_setprio(1);
#pragma unroll
      for (int nn = 0; nn < 6; ++nn) {
        int dd = dblk + nn * 16;
        bf16x8 vb = *reinterpret_cast<const bf16x8*>(VT + vt_off(dd + l15, g * 8));
        acc0[nn][0] *= rf0[0]; acc0[nn][1] *= rf0[1]; acc0[nn][2] *= rf0[2]; acc0[nn][3] *= rf0[3];
        acc0[nn] = __builtin_amdgcn_mfma_f32_16x16x32_bf16(pa0, vb, acc0[nn], 0, 0, 0);
        acc1[nn][0] *= rf1[0]; acc1[nn][1] *= rf1[1]; acc1[nn][2] *= rf1[2]; acc1[nn][3] *= rf1[3];
        acc1[nn] = __builtin_amdgcn_mfma_f32_16x16x32_bf16(pa1, vb, acc1[nn], 0, 0, 0);
      }
      __builtin_amdgcn_s_setprio(0);
    }
    asm volatile("s_waitcnt vmcnt(0)" ::: "memory");  // Ks[kt+1] resident
    __builtin_amdgcn_s_barrier();             // (a) for next iter
  }

  // ---- epilogue ----
  {
    float li0[4], li1[4];
#pragma unroll
    for (int r = 0; r < 4; ++r) {
      li0[r] = 1.0f / sm_l[pm * 32 + g * 4 + r];
      li1[r] = 1.0f / sm_l[pm * 32 + 16 + g * 4 + r];
    }
#pragma unroll
    for (int nn = 0; nn < 6; ++nn) {
      int dd = dblk + nn * 16 + l15;
#pragma unroll
      for (int r = 0; r < 4; ++r) {
        out[((size_t)b * Nn + q0 + pm * 32 + g * 4 + r) * Dn + dd] = acc0[nn][r] * li0[r];
        out[((size_t)b * Nn + q0 + pm * 32 + 16 + g * 4 + r) * Dn + dd] = acc1[nn][r] * li1[r];
      }
    }
  }
}

// =================== fallback: round-2 verified kernel (used if ws too small) ===================
constexpr int FQT = 32, FKT = 32;
constexpr int FQS_OFF = 0;
constexpr int FKS_OFF = FQS_OFF + FQT * Dn * 2;
constexpr int FVT_OFF = FKS_OFF + FKT * Dn * 2;
constexpr int FSP_OFF = FVT_OFF + Dn * FKT * 2;
constexpr int FP_OFF = FSP_OFF + 2 * FQT * 33 * 4;
constexpr int FSM_OFF = FP_OFF + FQT * FKT * 2;
constexpr int FSMEM = FSM_OFF + 3 * FQT * 4;
typedef __attribute__((ext_vector_type(4))) __bf16 bf16x4;

__device__ __forceinline__ bool keep_mask(int b, int q, int k) {
  uint32_t j = ((uint32_t)b << 22) | ((uint32_t)q << 11) | (uint32_t)k;
  uint32_t o0, o1;
  threefry2x32(0u, j, o0, o1);
  return ((o0 ^ o1) >> 31) == 0u;
}

__global__ __launch_bounds__(512, 2)
void attn_fallback(const float* __restrict__ in, float* __restrict__ out) {
  __shared__ __align__(16) unsigned char smem[FSMEM];
  unsigned char* Qs = smem + FQS_OFF;
  unsigned char* Ksm = smem + FKS_OFF;
  unsigned char* VTm = smem + FVT_OFF;
  float* Sp = (float*)(smem + FSP_OFF);
  unsigned char* Pm = smem + FP_OFF;
  float* sm_m = (float*)(smem + FSM_OFF);
  float* sm_l = sm_m + FQT;
  float* sm_rf = sm_m + 2 * FQT;
  const int t = threadIdx.x;
  const int L = blockIdx.x;
  const int b = ((L & 7) << 1) | ((L >> 3) & 1);
  const int q0 = (L >> 4) * FQT;
  const int w = t >> 6, l = t & 63, l15 = l & 15, g = l >> 4;
  const float scale = 0.03608439182435161f;
  const float* Qg = in + ((size_t)b * Nn + q0) * Dn;
  const float* Kg = in + (size_t)b * Nn * Dn;
  {
    int row = t >> 4, cbase = (t & 15) * 8;
    const float* src = Qg + (size_t)row * Dn;
#pragma unroll
    for (int i = 0; i < 6; ++i) {
      int d0 = cbase + 128 * i;
      f32x4 a = *reinterpret_cast<const f32x4*>(src + d0);
      f32x4 c = *reinterpret_cast<const f32x4*>(src + d0 + 4);
      bf16x8 h;
      h[0] = (__bf16)(a[0] * scale); h[1] = (__bf16)(a[1] * scale);
      h[2] = (__bf16)(a[2] * scale); h[3] = (__bf16)(a[3] * scale);
      h[4] = (__bf16)(c[0] * scale); h[5] = (__bf16)(c[1] * scale);
      h[6] = (__bf16)(c[2] * scale); h[7] = (__bf16)(c[3] * scale);
      *reinterpret_cast<bf16x8*>(Qs + qk_off(row, d0)) = h;
    }
  }
  if (t < FQT) { sm_m[t] = -1e30f; sm_l[t] = 0.0f; }
  f32x4 acc[12];
#pragma unroll
  for (int i = 0; i < 12; ++i) acc[i] = (f32x4){0.f, 0.f, 0.f, 0.f};
  const int qk_pair = w >> 1;
  const int qk_m = qk_pair >> 1, qk_n = qk_pair & 1, qk_h = w & 1;
  const int pv_m = w >> 2;
  const int pv_dblk = (w & 3) * 192;
#pragma unroll 1
  for (int kt = 0; kt < Nn / FKT; ++kt) {
    __syncthreads();
    {
      int row = t >> 4, cbase = (t & 15) * 8;
      const float* src = Kg + ((size_t)(kt * FKT + row)) * Dn;
#pragma unroll
      for (int i = 0; i < 6; ++i) {
        int d0 = cbase + 128 * i;
        f32x4 a = *reinterpret_cast<const f32x4*>(src + d0);
        f32x4 c = *reinterpret_cast<const f32x4*>(src + d0 + 4);
        bf16x8 h;
        h[0] = (__bf16)a[0]; h[1] = (__bf16)a[1]; h[2] = (__bf16)a[2]; h[3] = (__bf16)a[3];
        h[4] = (__bf16)c[0]; h[5] = (__bf16)c[1]; h[6] = (__bf16)c[2]; h[7] = (__bf16)c[3];
        *reinterpret_cast<bf16x8*>(Ksm + qk_off(row, d0)) = h;
      }
    }
    {
      const float* vsrc = Kg + ((size_t)(kt * FKT + 4 * w)) * Dn;
#pragma unroll
      for (int it = 0; it < 12; ++it) {
        int d = it * 64 + l;
        float v0 = vsrc[d], v1 = vsrc[Dn + d], v2 = vsrc[2 * Dn + d], v3 = vsrc[3 * Dn + d];
        bf16x4 hv;
        hv[0] = (__bf16)v0; hv[1] = (__bf16)v1; hv[2] = (__bf16)v2; hv[3] = (__bf16)v3;
        *reinterpret_cast<bf16x4*>(VTm + vt_off(d, 4 * w)) = hv;
      }
    }
    __syncthreads();
    {
      f32x4 s = (f32x4){0.f, 0.f, 0.f, 0.f};
#pragma unroll
      for (int dk = 0; dk < 12; ++dk) {
        int d = qk_h * 384 + dk * 32 + g * 8;
        bf16x8 aq = *reinterpret_cast<const bf16x8*>(Qs + qk_off(qk_m * 16 + l15, d));
        bf16x8 bk = *reinterpret_cast<const bf16x8*>(Ksm + qk_off(qk_n * 16 + l15, d));
        s = __builtin_amdgcn_mfma_f32_16x16x32_bf16(aq, bk, s, 0, 0, 0);
      }
      float* dst = Sp + qk_h * (FQT * 33) + (qk_m * 16 + g * 4) * 33 + qk_n * 16 + l15;
      dst[0] = s[0]; dst[33] = s[1]; dst[66] = s[2]; dst[99] = s[3];
    }
    __syncthreads();
    {
      int row = t >> 4, c = t & 15;
      float s0 = Sp[row * 33 + c] + Sp[FQT * 33 + row * 33 + c];
      float s1 = Sp[row * 33 + c + 16] + Sp[FQT * 33 + row * 33 + c + 16];
      float tmax = fmaxf(s0, s1);
#pragma unroll
      for (int mm = 1; mm <= 8; mm <<= 1) tmax = fmaxf(tmax, __shfl_xor(tmax, mm));
      float m_old = sm_m[row];
      float m_new = fmaxf(m_old, tmax);
      float p0 = __expf(s0 - m_new), p1 = __expf(s1 - m_new);
      float tsum = p0 + p1;
#pragma unroll
      for (int mm = 1; mm <= 8; mm <<= 1) tsum += __shfl_xor(tsum, mm);
      float rf = __expf(m_old - m_new);
      if (c == 0) {
        sm_m[row] = m_new;
        sm_l[row] = sm_l[row] * rf + tsum;
        sm_rf[row] = rf;
      }
      int qg = q0 + row, kg0 = kt * FKT + c;
      float pd0 = keep_mask(b, qg, kg0) ? 2.0f * p0 : 0.0f;
      float pd1 = keep_mask(b, qg, kg0 + 16) ? 2.0f * p1 : 0.0f;
      *reinterpret_cast<__bf16*>(Pm + p_off(row, c)) = (__bf16)pd0;
      *reinterpret_cast<__bf16*>(Pm + p_off(row, c + 16)) = (__bf16)pd1;
    }
    __syncthreads();
    {
      float rfv[4];
#pragma unroll
      for (int r = 0; r < 4; ++r) rfv[r] = sm_rf[pv_m * 16 + g * 4 + r];
      bf16x8 pa = *reinterpret_cast<const bf16x8*>(Pm + p_off(pv_m * 16 + l15, g * 8));
#pragma unroll
      for (int nn = 0; nn < 12; ++nn) {
        int d0 = pv_dblk + nn * 16;
        acc[nn][0] *= rfv[0]; acc[nn][1] *= rfv[1]; acc[nn][2] *= rfv[2]; acc[nn][3] *= rfv[3];
        bf16x8 vb = *reinterpret_cast<const bf16x8*>(VTm + vt_off(d0 + l15, g * 8));
        acc[nn] = __builtin_amdgcn_mfma_f32_16x16x32_bf16(pa, vb, acc[nn], 0, 0, 0);
      }
    }
  }
  __syncthreads();
  {
    float linv[4];
#pragma unroll
    for (int r = 0; r < 4; ++r) linv[r] = 1.0f / sm_l[pv_m * 16 + g * 4 + r];
#pragma unroll
    for (int nn = 0; nn < 12; ++nn) {
      int d = pv_dblk + nn * 16 + l15;
#pragma unroll
      for (int r = 0; r < 4; ++r) {
        int qg = q0 + pv_m * 16 + g * 4 + r;
        out[((size_t)b * Nn + qg) * Dn + d] = acc[nn][r] * linv[r];
      }
    }
  }
}

// =================== launcher ===================
extern "C" void kernel_launch(void* const* d_in, const int* in_sizes, int n_in,
                              void* d_out, int out_size, void* d_ws, size_t ws_size,
                              hipStream_t stream) {
  (void)in_sizes; (void)n_in; (void)out_size;
  const float* in = (const float*)d_in[0];
  float* out = (float*)d_out;
  constexpr size_t CVT_BYTES = (size_t)Bn * NT * TILEB;        // 50,331,648
  constexpr size_t MASK_BYTES = (size_t)Bn * Nn * Nn / 8;      // 8,388,608
  constexpr size_t WS_NEED = 2 * CVT_BYTES + MASK_BYTES;       // 109,051,904
  if (ws_size >= WS_NEED) {
    uint8_t* Kc = (uint8_t*)d_ws;
    uint8_t* Vc = Kc + CVT_BYTES;
    uint32_t* Mask = (uint32_t*)(Kc + 2 * CVT_BYTES);
    prepass_cvt<<<dim3(Bn * NT), dim3(256), 0, stream>>>(in, Kc, Vc);
    prepass_mask<<<dim3((Bn * Nn * Nn) / 256), dim3(256), 0, stream>>>(Mask);
    attn_main<<<dim3(512), dim3(1024), 0, stream>>>(Kc, Vc, Mask, out);
  } else {
    attn_fallback<<<dim3(Bn * (Nn / FQT)), dim3(512), 0, stream>>>(in, out);
  }
}